// Round 1
// baseline (34.556 us; speedup 1.0000x reference)
//
#include <hip/hip_runtime.h>
#include <hip/hip_bf16.h>

#define SCALE_F 173.71779276130078f   // 400 / ln(10)
#define TPT 8                         // tokens per thread
#define BLOCK 256

__global__ void zero_ws_kernel(float* ws, int n) {
    int i = blockIdx.x * 256 + threadIdx.x;
    if (i < n) ws[i] = 0.0f;
}

__global__ __launch_bounds__(BLOCK) void strength_main_kernel(
    const float* __restrict__ x,
    const float* __restrict__ W1,   // [6][32] row-major
    const float* __restrict__ b1,   // [32]
    const float* __restrict__ wr,   // [32]
    const float* __restrict__ brp,  // scalar
    const float* __restrict__ wz,   // [32]
    const float* __restrict__ bzp,  // scalar
    const int*   __restrict__ seg_ids,
    long N,
    float* __restrict__ num,        // [G]
    float* __restrict__ den)        // [G]
{
    __shared__ float Wl[192];
    __shared__ float b1l[32], wrl[32], wzl[32];

    const int tid  = threadIdx.x;
    const int lane = tid & 63;

    if (tid < 192) Wl[tid] = W1[tid];
    if (tid < 32) { b1l[tid] = b1[tid]; wrl[tid] = wr[tid]; wzl[tid] = wz[tid]; }
    __syncthreads();

    const float brv = *brp;
    const float bzv = *bzp;

    // wave w of this block covers tokens [block*2048 + w*512, +512); lane-interleaved per k
    const long base = (long)blockIdx.x * (BLOCK * TPT) + (long)(tid >> 6) * (64 * TPT) + lane;

    float xv[TPT][6];
    int   sg[TPT];

    #pragma unroll
    for (int k = 0; k < TPT; ++k) {
        long t = base + (long)k * 64;
        if (t < N) {
            const float* xp = x + t * 6;           // 24B rows -> 8B aligned
            float2 a = *reinterpret_cast<const float2*>(xp + 0);
            float2 b = *reinterpret_cast<const float2*>(xp + 2);
            float2 c = *reinterpret_cast<const float2*>(xp + 4);
            xv[k][0] = a.x; xv[k][1] = a.y;
            xv[k][2] = b.x; xv[k][3] = b.y;
            xv[k][4] = c.x; xv[k][5] = c.y;
            sg[k] = seg_ids[t];
        } else {
            #pragma unroll
            for (int i = 0; i < 6; ++i) xv[k][i] = 0.0f;
            sg[k] = 0x7fffffff;
        }
    }

    float r[TPT], z[TPT];
    #pragma unroll
    for (int k = 0; k < TPT; ++k) { r[k] = brv; z[k] = bzv; }

    // h_j = relu(x . W1[:,j] + b1_j);  r += h_j*wr_j;  z += h_j*wz_j
    #pragma unroll 4
    for (int j = 0; j < 32; ++j) {
        const float w0 = Wl[0 * 32 + j];
        const float w1 = Wl[1 * 32 + j];
        const float w2 = Wl[2 * 32 + j];
        const float w3 = Wl[3 * 32 + j];
        const float w4 = Wl[4 * 32 + j];
        const float w5 = Wl[5 * 32 + j];
        const float bj  = b1l[j];
        const float wrj = wrl[j];
        const float wzj = wzl[j];
        #pragma unroll
        for (int k = 0; k < TPT; ++k) {
            float h = fmaf(xv[k][0], w0,
                      fmaf(xv[k][1], w1,
                      fmaf(xv[k][2], w2,
                      fmaf(xv[k][3], w3,
                      fmaf(xv[k][4], w4,
                      fmaf(xv[k][5], w5, bj))))));
            h = fmaxf(h, 0.0f);
            r[k] = fmaf(h, wrj, r[k]);
            z[k] = fmaf(h, wzj, z[k]);
        }
    }

    // per-k wave-level segmented reduction, then one atomic per segment-run
    #pragma unroll
    for (int k = 0; k < TPT; ++k) {
        long t = base + (long)k * 64;
        bool valid = (t < N);
        int   s  = sg[k];
        float e  = valid ? __expf(z[k]) : 0.0f;   // no max-shift needed: |z| <~ 5
        float er = e * r[k];

        #pragma unroll
        for (int d = 1; d < 64; d <<= 1) {
            float e2  = __shfl_up(e, d);
            float er2 = __shfl_up(er, d);
            int   s2  = __shfl_up(s, d);
            if (lane >= d && s2 == s) { e += e2; er += er2; }
        }
        int snext = __shfl_down(s, 1);
        bool last = (lane == 63) || (snext != s);
        if (last && valid) {
            atomicAdd(&den[s], e);
            atomicAdd(&num[s], er);
        }
    }
}

__global__ void finalize_kernel(const float* __restrict__ num,
                                const float* __restrict__ den,
                                float* __restrict__ out, int G) {
    int g = blockIdx.x * 256 + threadIdx.x;
    if (g < G) {
        float d = den[g];
        out[g] = (d > 0.0f) ? (SCALE_F * num[g] / d) : 0.0f;
    }
}

extern "C" void kernel_launch(void* const* d_in, const int* in_sizes, int n_in,
                              void* d_out, int out_size, void* d_ws, size_t ws_size,
                              hipStream_t stream) {
    const float* x   = (const float*)d_in[0];
    const float* W1  = (const float*)d_in[1];
    const float* b1  = (const float*)d_in[2];
    const float* wr  = (const float*)d_in[3];
    const float* br  = (const float*)d_in[4];
    const float* wz  = (const float*)d_in[5];
    const float* bz  = (const float*)d_in[6];
    const int*   seg = (const int*)d_in[7];

    long N = in_sizes[7];          // token count from segment_ids
    int  G = out_size;             // 8192 segments

    float* num = (float*)d_ws;
    float* den = num + G;
    float* out = (float*)d_out;

    int zn = 2 * G;
    zero_ws_kernel<<<(zn + 255) / 256, 256, 0, stream>>>(num, zn);

    long tokens_per_block = (long)BLOCK * TPT;  // 2048
    int  nblocks = (int)((N + tokens_per_block - 1) / tokens_per_block);
    strength_main_kernel<<<nblocks, BLOCK, 0, stream>>>(
        x, W1, b1, wr, br, wz, bz, seg, N, num, den);

    finalize_kernel<<<(G + 255) / 256, 256, 0, stream>>>(num, den, out, G);
}